// Round 1
// baseline (510.067 us; speedup 1.0000x reference)
//
#include <hip/hip_runtime.h>
#include <hip/hip_bf16.h>

// Multi-head attention (B=2, S=2048, D_MODEL=1024, H=16, DK=64), causal.
// Outputs: out [B,S,DM] fp32  ++  attn_weights [B,H,S,S] fp32 (concatenated).

#define DM 1024
#define NH 16
#define DKH 64
#define BB 2
#define SS 2048
#define MM (BB*SS)   // 4096 rows

typedef __bf16 bf16_t;
typedef __bf16 bf16x4 __attribute__((ext_vector_type(4)));
typedef __bf16 bf16x8 __attribute__((ext_vector_type(8)));
typedef float  f32x4  __attribute__((ext_vector_type(4)));

// Load one MFMA operand fragment (16x16x32 bf16, split-half K layout):
// caller passes pointer to (row_or_col)*LD + k_base + 4*(lane>>4).
__device__ __forceinline__ bf16x8 frag_ld(const bf16_t* p) {
    bf16x4 lo = *(const bf16x4*)p;
    bf16x4 hi = *(const bf16x4*)(p + 16);
    bf16x8 r;
    r[0]=lo[0]; r[1]=lo[1]; r[2]=lo[2]; r[3]=lo[3];
    r[4]=hi[0]; r[5]=hi[1]; r[6]=hi[2]; r[7]=hi[3];
    return r;
}

// ---------------------------------------------------------------------------
// GEMM: C[M=4096, N=1024] = A[M,K=1024] @ W[N,K]^T + bias
// MODE 0: write bf16 head-split [B,H,S,DK] (projections q/k/v)
// MODE 1: write fp32 flat [M,DM] to d_out (output projection)
// AT: float (convert to bf16 on staging) or __bf16.
// ---------------------------------------------------------------------------
template<int MODE, typename AT>
__global__ __launch_bounds__(256)
void mha_gemm(const AT* __restrict__ A, const float* __restrict__ W,
              const float* __restrict__ bias, void* __restrict__ out)
{
    constexpr int BM = 128, BN = 128, BK = 32, LDA = BK + 4; // pad 4 -> conflict-free
    __shared__ bf16_t As[BM * LDA];
    __shared__ bf16_t Bs[BN * LDA];

    const int tid  = threadIdx.x;
    const int lane = tid & 63;
    const int wid  = tid >> 6;
    const int wm = wid >> 1, wn = wid & 1;        // 2x2 wave grid, 64x64 each
    const int bm = blockIdx.y, bn = blockIdx.x;
    const int c = lane & 15, g = lane >> 4;

    f32x4 acc[4][4] = {};

    for (int kt = 0; kt < DM / BK; ++kt) {
        __syncthreads();
        // stage A and W tiles (convert to bf16)
        #pragma unroll
        for (int i = 0; i < 4; ++i) {
            int idx = tid + i * 256;              // 1024 chunks of 4 elems
            int row = idx >> 3, cc = (idx & 7) * 4;
            bf16x4 va;
            const AT* asrc = A + (size_t)(bm * BM + row) * DM + kt * BK + cc;
            if constexpr (sizeof(AT) == 4) {
                float4 f = *(const float4*)asrc;
                va[0] = (bf16_t)f.x; va[1] = (bf16_t)f.y;
                va[2] = (bf16_t)f.z; va[3] = (bf16_t)f.w;
            } else {
                va = *(const bf16x4*)asrc;
            }
            *(bf16x4*)&As[row * LDA + cc] = va;

            const float* wsrc = W + (size_t)(bn * BN + row) * DM + kt * BK + cc;
            float4 fw = *(const float4*)wsrc;
            bf16x4 vb;
            vb[0] = (bf16_t)fw.x; vb[1] = (bf16_t)fw.y;
            vb[2] = (bf16_t)fw.z; vb[3] = (bf16_t)fw.w;
            *(bf16x4*)&Bs[row * LDA + cc] = vb;
        }
        __syncthreads();

        bf16x8 am[4], bnf[4];
        #pragma unroll
        for (int f = 0; f < 4; ++f)
            am[f] = frag_ld(&As[(wm * 64 + f * 16 + c) * LDA + 4 * g]);
        #pragma unroll
        for (int f = 0; f < 4; ++f)
            bnf[f] = frag_ld(&Bs[(wn * 64 + f * 16 + c) * LDA + 4 * g]);
        #pragma unroll
        for (int fm = 0; fm < 4; ++fm)
            #pragma unroll
            for (int fn = 0; fn < 4; ++fn)
                acc[fm][fn] = __builtin_amdgcn_mfma_f32_16x16x32_bf16(
                    am[fm], bnf[fn], acc[fm][fn], 0, 0, 0);
    }

    // epilogue: D[row][col]: col = lane&15, row = (lane>>4)*4 + reg  (m89)
    #pragma unroll
    for (int fm = 0; fm < 4; ++fm) {
        #pragma unroll
        for (int fn = 0; fn < 4; ++fn) {
            int col = bn * BN + wn * 64 + fn * 16 + c;
            float bcol = bias[col];
            #pragma unroll
            for (int r = 0; r < 4; ++r) {
                int row = bm * BM + wm * 64 + fm * 16 + 4 * g + r;
                float val = acc[fm][fn][r] + bcol;
                if constexpr (MODE == 0) {
                    int b = row >> 11, s = row & (SS - 1);
                    int h = col >> 6, dk = col & (DKH - 1);
                    ((bf16_t*)out)[((size_t)(b * NH + h) * SS + s) * DKH + dk] = (bf16_t)val;
                } else {
                    ((float*)out)[(size_t)row * DM + col] = val;
                }
            }
        }
    }
}

// ---------------------------------------------------------------------------
// Attention: one block = one (b,h) x 64-row q-tile. Two-pass (stats, then
// P-write + PV). Writes normalized P to attn (fp32) incl. zero upper triangle.
// ---------------------------------------------------------------------------
__global__ __launch_bounds__(256)
void mha_attn(const bf16_t* __restrict__ Qh, const bf16_t* __restrict__ Kh,
              const bf16_t* __restrict__ Vh, float* __restrict__ attn,
              bf16_t* __restrict__ aout)
{
    constexpr int LDS_ = 68;                     // 64 + 4 pad
    __shared__ bf16_t Ks[64 * LDS_];
    __shared__ bf16_t Vs[64 * LDS_];             // stored TRANSPOSED: [dk][key]
    __shared__ bf16_t Ps[64 * LDS_];             // [qrow][key] bf16

    const int tid = threadIdx.x, lane = tid & 63, w = tid >> 6;
    const int c = lane & 15, g = lane >> 4;
    const int qt = blockIdx.x, bh = blockIdx.y;
    const int q0 = qt * 64;

    const bf16_t* Qb = Qh + (size_t)bh * SS * DKH;
    const bf16_t* Kb = Kh + (size_t)bh * SS * DKH;
    const bf16_t* Vb = Vh + (size_t)bh * SS * DKH;
    float* attb = attn + (size_t)bh * SS * SS;

    // Q fragments held in registers for whole kernel (rows 16w..16w+15)
    bf16x8 qa[2];
    {
        const bf16_t* qp = Qb + (size_t)(q0 + w * 16 + c) * DKH;
        qa[0] = frag_ld(qp + 4 * g);
        qa[1] = frag_ld(qp + 32 + 4 * g);
    }

    float m[4], l[4];
    #pragma unroll
    for (int r = 0; r < 4; ++r) { m[r] = -3e38f; l[r] = 0.f; }

    // ---------------- pass 1: row max & sum ----------------
    for (int kt = 0; kt <= qt; ++kt) {
        __syncthreads();
        #pragma unroll
        for (int i = 0; i < 2; ++i) {
            int idx = tid + i * 256;
            int row = idx >> 3, cc = (idx & 7) * 8;
            const bf16_t* src = Kb + (size_t)(kt * 64 + row) * DKH + cc;
            *(bf16x4*)&Ks[row * LDS_ + cc]     = *(const bf16x4*)src;
            *(bf16x4*)&Ks[row * LDS_ + cc + 4] = *(const bf16x4*)(src + 4);
        }
        __syncthreads();

        f32x4 s[4] = {};
        #pragma unroll
        for (int fn = 0; fn < 4; ++fn) {
            bf16x8 b0 = frag_ld(&Ks[(fn * 16 + c) * LDS_ + 4 * g]);
            bf16x8 b1 = frag_ld(&Ks[(fn * 16 + c) * LDS_ + 32 + 4 * g]);
            s[fn] = __builtin_amdgcn_mfma_f32_16x16x32_bf16(qa[0], b0, s[fn], 0, 0, 0);
            s[fn] = __builtin_amdgcn_mfma_f32_16x16x32_bf16(qa[1], b1, s[fn], 0, 0, 0);
        }

        const bool diag = (kt == qt);
        float sv[4][4], tm[4];
        #pragma unroll
        for (int r = 0; r < 4; ++r) tm[r] = -3e38f;
        #pragma unroll
        for (int fn = 0; fn < 4; ++fn)
            #pragma unroll
            for (int r = 0; r < 4; ++r) {
                float x = s[fn][r] * 0.125f;
                if (diag && (fn * 16 + c > w * 16 + 4 * g + r)) x = -3e38f;
                sv[fn][r] = x;
                tm[r] = fmaxf(tm[r], x);
            }
        #pragma unroll
        for (int off = 1; off < 16; off <<= 1)
            #pragma unroll
            for (int r = 0; r < 4; ++r) tm[r] = fmaxf(tm[r], __shfl_xor(tm[r], off));

        #pragma unroll
        for (int r = 0; r < 4; ++r) {
            float mn = fmaxf(m[r], tm[r]);
            float rs = 0.f;
            #pragma unroll
            for (int fn = 0; fn < 4; ++fn) rs += __expf(sv[fn][r] - mn);
            #pragma unroll
            for (int off = 1; off < 16; off <<= 1) rs += __shfl_xor(rs, off);
            l[r] = l[r] * __expf(m[r] - mn) + rs;
            m[r] = mn;
        }
    }

    float invl[4];
    #pragma unroll
    for (int r = 0; r < 4; ++r) invl[r] = 1.f / l[r];

    // ---------------- pass 2: P write + PV ----------------
    f32x4 o[4] = {};
    for (int kt = 0; kt <= qt; ++kt) {
        __syncthreads();
        #pragma unroll
        for (int i = 0; i < 2; ++i) {
            int idx = tid + i * 256;
            int row = idx >> 3, cc = (idx & 7) * 8;
            const bf16_t* src = Kb + (size_t)(kt * 64 + row) * DKH + cc;
            *(bf16x4*)&Ks[row * LDS_ + cc]     = *(const bf16x4*)src;
            *(bf16x4*)&Ks[row * LDS_ + cc + 4] = *(const bf16x4*)(src + 4);
            // V staged transposed: Vs[dk][key]
            const bf16_t* vsrc = Vb + (size_t)(kt * 64 + row) * DKH + cc;
            bf16x4 v0 = *(const bf16x4*)vsrc;
            bf16x4 v1 = *(const bf16x4*)(vsrc + 4);
            #pragma unroll
            for (int j = 0; j < 4; ++j) Vs[(cc + j) * LDS_ + row]     = v0[j];
            #pragma unroll
            for (int j = 0; j < 4; ++j) Vs[(cc + 4 + j) * LDS_ + row] = v1[j];
        }
        __syncthreads();

        f32x4 s[4] = {};
        #pragma unroll
        for (int fn = 0; fn < 4; ++fn) {
            bf16x8 b0 = frag_ld(&Ks[(fn * 16 + c) * LDS_ + 4 * g]);
            bf16x8 b1 = frag_ld(&Ks[(fn * 16 + c) * LDS_ + 32 + 4 * g]);
            s[fn] = __builtin_amdgcn_mfma_f32_16x16x32_bf16(qa[0], b0, s[fn], 0, 0, 0);
            s[fn] = __builtin_amdgcn_mfma_f32_16x16x32_bf16(qa[1], b1, s[fn], 0, 0, 0);
        }

        const bool diag = (kt == qt);
        #pragma unroll
        for (int fn = 0; fn < 4; ++fn)
            #pragma unroll
            for (int r = 0; r < 4; ++r) {
                float x = s[fn][r] * 0.125f;
                bool msk = diag && (fn * 16 + c > w * 16 + 4 * g + r);
                float p = msk ? 0.f : __expf(x - m[r]) * invl[r];
                Ps[(w * 16 + 4 * g + r) * LDS_ + fn * 16 + c] = (bf16_t)p;
            }

        // PV: A = P (own wave's rows -> no block barrier needed), B = Vs[dk][key]
        bf16x8 pa0 = frag_ld(&Ps[(w * 16 + c) * LDS_ + 4 * g]);
        bf16x8 pa1 = frag_ld(&Ps[(w * 16 + c) * LDS_ + 32 + 4 * g]);
        #pragma unroll
        for (int fn = 0; fn < 4; ++fn) {
            bf16x8 v0 = frag_ld(&Vs[(fn * 16 + c) * LDS_ + 4 * g]);
            bf16x8 v1 = frag_ld(&Vs[(fn * 16 + c) * LDS_ + 32 + 4 * g]);
            o[fn] = __builtin_amdgcn_mfma_f32_16x16x32_bf16(pa0, v0, o[fn], 0, 0, 0);
            o[fn] = __builtin_amdgcn_mfma_f32_16x16x32_bf16(pa1, v1, o[fn], 0, 0, 0);
        }

        __syncthreads();   // all waves' Ps rows visible
        // coalesced fp32 attn write from Ps: thread t -> row t>>2, 16 cols
        {
            int row = tid >> 2, cc = (tid & 3) * 16;
            float* dst = attb + (size_t)(q0 + row) * SS + kt * 64 + cc;
            #pragma unroll
            for (int j4 = 0; j4 < 4; ++j4) {
                bf16x4 pv = *(const bf16x4*)&Ps[row * LDS_ + cc + j4 * 4];
                float4 fo;
                fo.x = (float)pv[0]; fo.y = (float)pv[1];
                fo.z = (float)pv[2]; fo.w = (float)pv[3];
                *(float4*)(dst + j4 * 4) = fo;
            }
        }
    }

    // epilogue: O -> aout (bf16, [M, DM] with head interleave)
    {
        int b = bh >> 4, h = bh & 15;
        #pragma unroll
        for (int fn = 0; fn < 4; ++fn)
            #pragma unroll
            for (int r = 0; r < 4; ++r) {
                int qrow = q0 + w * 16 + 4 * g + r;
                int dk = fn * 16 + c;
                aout[(size_t)(b * SS + qrow) * DM + h * DKH + dk] = (bf16_t)o[fn][r];
            }
    }

    // zero-fill masked upper region (k >= (qt+1)*64)
    {
        int kend = (qt + 1) * 64;
        float4 z; z.x = z.y = z.z = z.w = 0.f;
        for (int r = 0; r < 64; ++r) {
            float* dst = attb + (size_t)(q0 + r) * SS;
            for (int cc = kend + tid * 4; cc < SS; cc += 256 * 4)
                *(float4*)(dst + cc) = z;
        }
    }
}

// ---------------------------------------------------------------------------
extern "C" void kernel_launch(void* const* d_in, const int* in_sizes, int n_in,
                              void* d_out, int out_size, void* d_ws, size_t ws_size,
                              hipStream_t stream)
{
    const float* q   = (const float*)d_in[0];
    const float* k   = (const float*)d_in[1];
    const float* v   = (const float*)d_in[2];
    // d_in[3] = causal mask, known analytically -> unused
    const float* w_q = (const float*)d_in[4];
    const float* b_q = (const float*)d_in[5];
    const float* w_k = (const float*)d_in[6];
    const float* b_k = (const float*)d_in[7];
    const float* w_v = (const float*)d_in[8];
    const float* b_v = (const float*)d_in[9];
    const float* w_o = (const float*)d_in[10];
    const float* b_o = (const float*)d_in[11];

    float* out   = (float*)d_out;
    float* attnw = out + (size_t)MM * DM;

    bf16_t* Qh   = (bf16_t*)d_ws;                 // [B,H,S,DK] bf16
    bf16_t* Kh   = Qh + (size_t)MM * DM;
    bf16_t* Vh   = Kh + (size_t)MM * DM;
    bf16_t* aout = Vh + (size_t)MM * DM;          // [M, DM] bf16

    dim3 gg(DM / 128, MM / 128);                  // (8, 32)
    mha_gemm<0, float><<<gg, 256, 0, stream>>>(q, w_q, b_q, Qh);
    mha_gemm<0, float><<<gg, 256, 0, stream>>>(k, w_k, b_k, Kh);
    mha_gemm<0, float><<<gg, 256, 0, stream>>>(v, w_v, b_v, Vh);

    mha_attn<<<dim3(SS / 64, BB * NH), 256, 0, stream>>>(Qh, Kh, Vh, attnw, aout);

    mha_gemm<1, bf16_t><<<gg, 256, 0, stream>>>(aout, w_o, b_o, out);
}

// Round 2
// 382.127 us; speedup vs baseline: 1.3348x; 1.3348x over previous
//
#include <hip/hip_runtime.h>
#include <hip/hip_bf16.h>

// Multi-head attention (B=2, S=2048, D_MODEL=1024, H=16, DK=64), causal.
// Outputs: out [B,S,DM] fp32  ++  attn_weights [B,H,S,S] fp32 (concatenated).

#define DM 1024
#define NH 16
#define DKH 64
#define BB 2
#define SS 2048
#define MM (BB*SS)   // 4096 rows

typedef __bf16 bf16_t;
typedef __bf16 bf16x4 __attribute__((ext_vector_type(4)));
typedef __bf16 bf16x8 __attribute__((ext_vector_type(8)));
typedef float  f32x4  __attribute__((ext_vector_type(4)));

// async global->LDS, 16B per lane. LDS dest must be wave-uniform base;
// HW adds lane*16. Global src is per-lane.
__device__ __forceinline__ void gload16(const bf16_t* g, bf16_t* l) {
    __builtin_amdgcn_global_load_lds(
        (const __attribute__((address_space(1))) void*)g,
        (__attribute__((address_space(3))) void*)l, 16, 0, 0);
}

// MFMA operand fragment from padded (conflict-free) LDS or global:
// elems j=0..3 at k=4g+j, j=4..7 at k=4g+16+j  (validated in round 0).
__device__ __forceinline__ bf16x8 frag_ld(const bf16_t* p) {
    bf16x4 lo = *(const bf16x4*)p;
    bf16x4 hi = *(const bf16x4*)(p + 16);
    bf16x8 r;
    r[0]=lo[0]; r[1]=lo[1]; r[2]=lo[2]; r[3]=lo[3];
    r[4]=hi[0]; r[5]=hi[1]; r[6]=hi[2]; r[7]=hi[3];
    return r;
}

// Fragment read from LINEAR [128][64] bf16 LDS tile staged with the
// source-side XOR swizzle: 16B chunk s of row r holds global chunk s^(r&7).
// kh = which 32-wide k-half of the 64-wide tile.
__device__ __forceinline__ bf16x8 frag_swz(const bf16_t* tile, int row, int kh, int g) {
    const int c0  = kh * 4 + (g >> 1);
    const int sub = (g & 1) * 4;
    const int r7  = row & 7;
    const bf16_t* p0 = tile + row * 64 + (((c0    ) ^ r7) << 3) + sub;
    const bf16_t* p1 = tile + row * 64 + (((c0 + 2) ^ r7) << 3) + sub;
    bf16x4 lo = *(const bf16x4*)p0;
    bf16x4 hi = *(const bf16x4*)p1;
    bf16x8 r;
    r[0]=lo[0]; r[1]=lo[1]; r[2]=lo[2]; r[3]=lo[3];
    r[4]=hi[0]; r[5]=hi[1]; r[6]=hi[2]; r[7]=hi[3];
    return r;
}

// ---------------------------------------------------------------------------
// fp32 -> bf16 batch convert (blockIdx.y selects tensor), 8 elems/thread
// ---------------------------------------------------------------------------
__global__ __launch_bounds__(256)
void cvt_bf16(const float* __restrict__ s0, const float* __restrict__ s1,
              const float* __restrict__ s2, const float* __restrict__ s3,
              bf16_t* __restrict__ d0, bf16_t* __restrict__ d1,
              bf16_t* __restrict__ d2, bf16_t* __restrict__ d3)
{
    const float* ss[4] = {s0, s1, s2, s3};
    bf16_t*      dd[4] = {d0, d1, d2, d3};
    const float* s = ss[blockIdx.y];
    bf16_t*      d = dd[blockIdx.y];
    size_t i = (size_t)(blockIdx.x * 256 + threadIdx.x) * 8;
    float4 f0 = *(const float4*)(s + i);
    float4 f1 = *(const float4*)(s + i + 4);
    bf16x8 v;
    v[0]=(bf16_t)f0.x; v[1]=(bf16_t)f0.y; v[2]=(bf16_t)f0.z; v[3]=(bf16_t)f0.w;
    v[4]=(bf16_t)f1.x; v[5]=(bf16_t)f1.y; v[6]=(bf16_t)f1.z; v[7]=(bf16_t)f1.w;
    *(bf16x8*)(d + i) = v;
}

// ---------------------------------------------------------------------------
// GEMM: C[4096,1024] = A[M,K] @ W[N,K]^T + bias, all bf16 in, m97-style:
// 128x128 tile, BK=64, global_load_lds(16B) into linear LDS with
// source-side XOR swizzle, swizzled ds reads (conflict-free).
// MODE 0: write bf16 head-split [B,H,S,DK];  MODE 1: fp32 flat to d_out.
// ---------------------------------------------------------------------------
template<int MODE>
__global__ __launch_bounds__(256)
void mha_gemm2(const bf16_t* __restrict__ A, const bf16_t* __restrict__ W,
               const float* __restrict__ bias, void* __restrict__ out)
{
    __shared__ bf16_t As[128 * 64];
    __shared__ bf16_t Bs[128 * 64];

    const int tid  = threadIdx.x;
    const int lane = tid & 63;
    const int wid  = tid >> 6;
    const int wm = wid >> 1, wn = wid & 1;        // 2x2 wave grid, 64x64 each
    const int bm = blockIdx.y, bn = blockIdx.x;
    const int c = lane & 15, g = lane >> 4;
    const int lr = lane >> 3, ls = lane & 7;      // staging row-in-8 / chunk slot
    const int scol = ((ls ^ lr) << 3);            // pre-swizzled source col (elems)

    f32x4 acc[4][4] = {};

    const bf16_t* Ab = A + (size_t)(bm * 128 + wid * 32 + lr) * DM + scol;
    const bf16_t* Wb = W + (size_t)(bn * 128 + wid * 32 + lr) * DM + scol;
    bf16_t* Asl = &As[(wid * 32) * 64];
    bf16_t* Bsl = &Bs[(wid * 32) * 64];

    for (int kt = 0; kt < DM / 64; ++kt) {
        __syncthreads();
        #pragma unroll
        for (int j = 0; j < 4; ++j) {
            gload16(Ab + (size_t)j * 8 * DM + kt * 64, Asl + j * 8 * 64);
            gload16(Wb + (size_t)j * 8 * DM + kt * 64, Bsl + j * 8 * 64);
        }
        __syncthreads();

        #pragma unroll
        for (int kh = 0; kh < 2; ++kh) {
            bf16x8 am[4], bw[4];
            #pragma unroll
            for (int f = 0; f < 4; ++f) am[f] = frag_swz(As, wm * 64 + f * 16 + c, kh, g);
            #pragma unroll
            for (int f = 0; f < 4; ++f) bw[f] = frag_swz(Bs, wn * 64 + f * 16 + c, kh, g);
            #pragma unroll
            for (int fm = 0; fm < 4; ++fm)
                #pragma unroll
                for (int fn = 0; fn < 4; ++fn)
                    acc[fm][fn] = __builtin_amdgcn_mfma_f32_16x16x32_bf16(
                        am[fm], bw[fn], acc[fm][fn], 0, 0, 0);
        }
    }

    // epilogue: D[row][col]: col = lane&15, row = (lane>>4)*4 + reg
    #pragma unroll
    for (int fm = 0; fm < 4; ++fm) {
        #pragma unroll
        for (int fn = 0; fn < 4; ++fn) {
            int col = bn * 128 + wn * 64 + fn * 16 + c;
            float bcol = bias[col];
            #pragma unroll
            for (int r = 0; r < 4; ++r) {
                int row = bm * 128 + wm * 64 + fm * 16 + 4 * g + r;
                float val = acc[fm][fn][r] + bcol;
                if constexpr (MODE == 0) {
                    int b = row >> 11, s = row & (SS - 1);
                    int h = col >> 6, dk = col & (DKH - 1);
                    ((bf16_t*)out)[((size_t)(b * NH + h) * SS + s) * DKH + dk] = (bf16_t)val;
                } else {
                    ((float*)out)[(size_t)row * DM + col] = val;
                }
            }
        }
    }
}

// ---------------------------------------------------------------------------
// Attention: one block = one (b,h) x 128-row q-tile, 8 waves (512 thr).
// Two passes (stats, then P-write + PV). Heavy-first block order.
// ---------------------------------------------------------------------------
__global__ __launch_bounds__(512)
void mha_attn2(const bf16_t* __restrict__ Qh, const bf16_t* __restrict__ Kh,
               const bf16_t* __restrict__ Vh, float* __restrict__ attn,
               bf16_t* __restrict__ aout)
{
    constexpr int LDW = 68;                      // 64 + 4 pad -> conflict-free
    __shared__ bf16_t Ks[64 * LDW];
    __shared__ bf16_t Vs[64 * LDW];              // stored TRANSPOSED: [dk][key]
    __shared__ bf16_t Ps[128 * LDW];             // [qrow][key] bf16

    const int tid = threadIdx.x, lane = tid & 63, w = tid >> 6;
    const int c = lane & 15, g = lane >> 4;
    const int qt = (gridDim.x - 1) - blockIdx.x; // heavy blocks dispatch first
    const int bh = blockIdx.y;
    const int q0 = qt * 128;
    const int ntile = 2 * qt + 2;
    const int wrow0 = q0 + w * 16;               // wave's first q row

    const bf16_t* Qb = Qh + (size_t)bh * SS * DKH;
    const bf16_t* Kb = Kh + (size_t)bh * SS * DKH;
    const bf16_t* Vb = Vh + (size_t)bh * SS * DKH;
    float* attb = attn + (size_t)bh * SS * SS;

    // Q fragments in registers for whole kernel (wave rows wrow0..wrow0+15)
    bf16x8 qa0, qa1;
    {
        const bf16_t* qp = Qb + (size_t)(wrow0 + c) * DKH + 4 * g;
        qa0 = frag_ld(qp);
        qa1 = frag_ld(qp + 32);
    }

    float m[4], l[4];
    #pragma unroll
    for (int r = 0; r < 4; ++r) { m[r] = -3e38f; l[r] = 0.f; }

    const int srow = tid >> 3, scc = (tid & 7) * 8;   // staging map (64x64 tile)

    // ---------------- pass 1: row max & sum ----------------
    for (int kt = 0; kt < ntile; ++kt) {
        __syncthreads();
        {
            bf16x8 kv = *(const bf16x8*)(Kb + (size_t)(kt * 64 + srow) * DKH + scc);
            *(bf16x4*)&Ks[srow * LDW + scc]     = __builtin_shufflevector(kv, kv, 0, 1, 2, 3);
            *(bf16x4*)&Ks[srow * LDW + scc + 4] = __builtin_shufflevector(kv, kv, 4, 5, 6, 7);
        }
        __syncthreads();
        if (kt * 64 <= wrow0 + 15) {             // wave has live rows this tile
            f32x4 s[4] = {};
            #pragma unroll
            for (int fn = 0; fn < 4; ++fn) {
                bf16x8 b0 = frag_ld(&Ks[(fn * 16 + c) * LDW + 4 * g]);
                bf16x8 b1 = frag_ld(&Ks[(fn * 16 + c) * LDW + 32 + 4 * g]);
                s[fn] = __builtin_amdgcn_mfma_f32_16x16x32_bf16(qa0, b0, s[fn], 0, 0, 0);
                s[fn] = __builtin_amdgcn_mfma_f32_16x16x32_bf16(qa1, b1, s[fn], 0, 0, 0);
            }
            const bool amask = (kt * 64 + 63) > wrow0;
            float sv[4][4], tm[4];
            #pragma unroll
            for (int r = 0; r < 4; ++r) tm[r] = -3e38f;
            #pragma unroll
            for (int fn = 0; fn < 4; ++fn)
                #pragma unroll
                for (int r = 0; r < 4; ++r) {
                    float x = s[fn][r] * 0.125f;
                    if (amask && (kt * 64 + fn * 16 + c > wrow0 + 4 * g + r)) x = -3e38f;
                    sv[fn][r] = x;
                    tm[r] = fmaxf(tm[r], x);
                }
            #pragma unroll
            for (int off = 1; off < 16; off <<= 1)
                #pragma unroll
                for (int r = 0; r < 4; ++r) tm[r] = fmaxf(tm[r], __shfl_xor(tm[r], off));
            #pragma unroll
            for (int r = 0; r < 4; ++r) {
                float mn = fmaxf(m[r], tm[r]);
                float rs = 0.f;
                #pragma unroll
                for (int fn = 0; fn < 4; ++fn) rs += __expf(sv[fn][r] - mn);
                #pragma unroll
                for (int off = 1; off < 16; off <<= 1) rs += __shfl_xor(rs, off);
                l[r] = l[r] * __expf(m[r] - mn) + rs;
                m[r] = mn;
            }
        }
    }

    float invl[4];
    #pragma unroll
    for (int r = 0; r < 4; ++r) invl[r] = 1.f / l[r];

    // ---------------- pass 2: P write + PV ----------------
    f32x4 o[4] = {};
    for (int kt = 0; kt < ntile; ++kt) {
        __syncthreads();
        {
            bf16x8 kv = *(const bf16x8*)(Kb + (size_t)(kt * 64 + srow) * DKH + scc);
            *(bf16x4*)&Ks[srow * LDW + scc]     = __builtin_shufflevector(kv, kv, 0, 1, 2, 3);
            *(bf16x4*)&Ks[srow * LDW + scc + 4] = __builtin_shufflevector(kv, kv, 4, 5, 6, 7);
            bf16x8 vv = *(const bf16x8*)(Vb + (size_t)(kt * 64 + srow) * DKH + scc);
            #pragma unroll
            for (int j = 0; j < 8; ++j) Vs[(scc + j) * LDW + srow] = vv[j];
        }
        __syncthreads();

        const bool dead = kt * 64 > wrow0 + 15;
        if (dead) {
            // rows fully masked this tile: P = 0
            #pragma unroll
            for (int fn = 0; fn < 4; ++fn)
                #pragma unroll
                for (int r = 0; r < 4; ++r)
                    Ps[(w * 16 + 4 * g + r) * LDW + fn * 16 + c] = (bf16_t)0.f;
        } else {
            f32x4 s[4] = {};
            #pragma unroll
            for (int fn = 0; fn < 4; ++fn) {
                bf16x8 b0 = frag_ld(&Ks[(fn * 16 + c) * LDW + 4 * g]);
                bf16x8 b1 = frag_ld(&Ks[(fn * 16 + c) * LDW + 32 + 4 * g]);
                s[fn] = __builtin_amdgcn_mfma_f32_16x16x32_bf16(qa0, b0, s[fn], 0, 0, 0);
                s[fn] = __builtin_amdgcn_mfma_f32_16x16x32_bf16(qa1, b1, s[fn], 0, 0, 0);
            }
            const bool amask = (kt * 64 + 63) > wrow0;
            #pragma unroll
            for (int fn = 0; fn < 4; ++fn)
                #pragma unroll
                for (int r = 0; r < 4; ++r) {
                    float x = s[fn][r] * 0.125f;
                    bool msk = amask && (kt * 64 + fn * 16 + c > wrow0 + 4 * g + r);
                    float p = msk ? 0.f : __expf(x - m[r]) * invl[r];
                    Ps[(w * 16 + 4 * g + r) * LDW + fn * 16 + c] = (bf16_t)p;
                }
            // PV on own wave's rows (no cross-wave dependency)
            bf16x8 pa0 = frag_ld(&Ps[(w * 16 + c) * LDW + 4 * g]);
            bf16x8 pa1 = frag_ld(&Ps[(w * 16 + c) * LDW + 32 + 4 * g]);
            #pragma unroll
            for (int fn = 0; fn < 4; ++fn) {
                bf16x8 v0 = frag_ld(&Vs[(fn * 16 + c) * LDW + 4 * g]);
                bf16x8 v1 = frag_ld(&Vs[(fn * 16 + c) * LDW + 32 + 4 * g]);
                o[fn] = __builtin_amdgcn_mfma_f32_16x16x32_bf16(pa0, v0, o[fn], 0, 0, 0);
                o[fn] = __builtin_amdgcn_mfma_f32_16x16x32_bf16(pa1, v1, o[fn], 0, 0, 0);
            }
        }

        __syncthreads();   // all waves' Ps rows visible
        {
            int row = tid >> 2, cc2 = (tid & 3) * 16;
            float* dst = attb + (size_t)(q0 + row) * SS + kt * 64 + cc2;
            #pragma unroll
            for (int j4 = 0; j4 < 4; ++j4) {
                bf16x4 pv = *(const bf16x4*)&Ps[row * LDW + cc2 + j4 * 4];
                float4 fo;
                fo.x = (float)pv[0]; fo.y = (float)pv[1];
                fo.z = (float)pv[2]; fo.w = (float)pv[3];
                *(float4*)(dst + j4 * 4) = fo;
            }
        }
    }

    // epilogue: O -> aout (bf16, [M, DM] head-interleaved)
    {
        int b = bh >> 4, h = bh & 15;
        #pragma unroll
        for (int fn = 0; fn < 4; ++fn)
            #pragma unroll
            for (int r = 0; r < 4; ++r) {
                int qrow = wrow0 + 4 * g + r;
                int dk = fn * 16 + c;
                aout[(size_t)(b * SS + qrow) * DM + h * DKH + dk] = (bf16_t)o[fn][r];
            }
    }

    // zero-fill masked region (k >= q0+128)
    {
        int kend = q0 + 128;
        float4 z; z.x = z.y = z.z = z.w = 0.f;
        for (int r = 0; r < 128; ++r) {
            float* dst = attb + (size_t)(q0 + r) * SS;
            for (int cc2 = kend + tid * 4; cc2 < SS; cc2 += 512 * 4)
                *(float4*)(dst + cc2) = z;
        }
    }
}

// ---------------------------------------------------------------------------
extern "C" void kernel_launch(void* const* d_in, const int* in_sizes, int n_in,
                              void* d_out, int out_size, void* d_ws, size_t ws_size,
                              hipStream_t stream)
{
    const float* q   = (const float*)d_in[0];
    const float* k   = (const float*)d_in[1];
    const float* v   = (const float*)d_in[2];
    // d_in[3] = causal mask, known analytically -> unused
    const float* w_q = (const float*)d_in[4];
    const float* b_q = (const float*)d_in[5];
    const float* w_k = (const float*)d_in[6];
    const float* b_k = (const float*)d_in[7];
    const float* w_v = (const float*)d_in[8];
    const float* b_v = (const float*)d_in[9];
    const float* w_o = (const float*)d_in[10];
    const float* b_o = (const float*)d_in[11];

    float* out   = (float*)d_out;
    float* attnw = out + (size_t)MM * DM;

    bf16_t* Qh   = (bf16_t*)d_ws;                 // [B,H,S,DK] bf16
    bf16_t* Kh   = Qh + (size_t)MM * DM;
    bf16_t* Vh   = Kh + (size_t)MM * DM;
    bf16_t* aout = Vh + (size_t)MM * DM;          // [M, DM] bf16
    bf16_t* qb   = aout + (size_t)MM * DM;        // bf16 copies of inputs
    bf16_t* kb   = qb + (size_t)MM * DM;
    bf16_t* vb   = kb + (size_t)MM * DM;
    bf16_t* wqb  = vb + (size_t)MM * DM;          // bf16 weights [DM][DM]
    bf16_t* wkb  = wqb + (size_t)DM * DM;
    bf16_t* wvb  = wkb + (size_t)DM * DM;
    bf16_t* wob  = wvb + (size_t)DM * DM;

    cvt_bf16<<<dim3(MM * DM / 2048, 3), 256, 0, stream>>>(q, k, v, q, qb, kb, vb, qb);
    cvt_bf16<<<dim3(DM * DM / 2048, 4), 256, 0, stream>>>(w_q, w_k, w_v, w_o,
                                                          wqb, wkb, wvb, wob);

    dim3 gg(DM / 128, MM / 128);                  // (8, 32)
    mha_gemm2<0><<<gg, 256, 0, stream>>>(qb, wqb, b_q, Qh);
    mha_gemm2<0><<<gg, 256, 0, stream>>>(kb, wkb, b_k, Kh);
    mha_gemm2<0><<<gg, 256, 0, stream>>>(vb, wvb, b_v, Vh);

    mha_attn2<<<dim3(SS / 128, BB * NH), 512, 0, stream>>>(Qh, Kh, Vh, attnw, aout);

    mha_gemm2<1><<<gg, 256, 0, stream>>>(aout, wob, b_o, out);
}